// Round 12
// baseline (293.954 us; speedup 1.0000x reference)
//
#include <hip/hip_runtime.h>

// DeformableGCN: 3x mean-smoothing + 2x attention-weighted GCN conv.
// R7-R10: branchless half8 gathers, two nodes/wave, partition-parallel
// LDS bin-sort CSR, ushort4 index loads.
// R11: fused transforms into gathers — WIN on data movement, LOSS on the
// in-gather broadcast GEMV (~30us of shfl/LDS overhead in mean3_xf1).
// R12: GEMVs moved to tiny dedicated kernels (xform1z, xform2z, shfl-based,
// no LDS/barrier); gathers keep only cheap epilogues (xs build + attention
// dots). h1 stored fp16. 10 dispatches.

typedef __attribute__((ext_vector_type(8))) _Float16 half8;

#define CHUNK 2048

// ---- pass A: bin edges into partition-sorted chunks + x->fp16 convert ----
__global__ void binA_kernel(const int* __restrict__ src, const int* __restrict__ dst,
                            unsigned int* __restrict__ packed, int* __restrict__ offs,
                            const float* __restrict__ x, _Float16* __restrict__ x16,
                            int total8, int E) {
    __shared__ int cnt[256];
    __shared__ int pref[256];
    __shared__ int cur[256];
    __shared__ unsigned int stage[CHUNK];
    int t = threadIdx.x;
    int base = blockIdx.x * CHUNK;
    int len = E - base; if (len > CHUNK) len = CHUNK;
    cnt[t] = 0;
    __syncthreads();
    for (int i = t; i < len; i += 256) atomicAdd(&cnt[dst[base + i] >> 8], 1);
    __syncthreads();
    int v = cnt[t];
    pref[t] = v;
    __syncthreads();
    for (int off = 1; off < 256; off <<= 1) {
        int u = (t >= off) ? pref[t - off] : 0;
        __syncthreads();
        pref[t] += u;
        __syncthreads();
    }
    int excl = pref[t] - v;
    cur[t] = excl;
    offs[blockIdx.x * 257 + t] = excl;
    if (t == 255) offs[blockIdx.x * 257 + 256] = pref[255];
    __syncthreads();
    for (int i = t; i < len; i += 256) {
        int s = src[base + i], d = dst[base + i];
        int pos = atomicAdd(&cur[d >> 8], 1);
        stage[pos] = (unsigned int)s | ((unsigned int)d << 16);
    }
    __syncthreads();
    for (int i = t; i < len; i += 256) packed[base + i] = stage[i];
    for (int i = blockIdx.x * 256 + t; i < total8; i += gridDim.x * 256) {
        float4 v0 = ((const float4*)x)[2 * i];
        float4 v1 = ((const float4*)x)[2 * i + 1];
        half8 o;
        o[0] = (_Float16)v0.x; o[1] = (_Float16)v0.y; o[2] = (_Float16)v0.z; o[3] = (_Float16)v0.w;
        o[4] = (_Float16)v1.x; o[5] = (_Float16)v1.y; o[6] = (_Float16)v1.z; o[7] = (_Float16)v1.w;
        ((half8*)x16)[i] = o;
    }
}

// ---- per-partition degree count: dense deg write + aligned total ----
__global__ void binB_count_kernel(const unsigned int* __restrict__ packed,
                                  const int* __restrict__ offs,
                                  int* __restrict__ deg, int* __restrict__ partTot,
                                  int nChunks, int N) {
    __shared__ int cnt[256];
    __shared__ int red[256];
    int t = threadIdx.x;
    int p = blockIdx.x;
    cnt[t] = 0;
    __syncthreads();
    for (int c = t; c < nChunks; c += 256) {
        const int* oc = offs + c * 257;
        int o0 = oc[p], o1 = oc[p + 1];
        const unsigned int* pk = packed + (size_t)c * CHUNK;
        for (int i = o0; i < o1; ++i) atomicAdd(&cnt[(pk[i] >> 16) & 255], 1);
    }
    __syncthreads();
    int node = p * 256 + t;
    int c = cnt[t];
    if (node < N) deg[node] = c;
    red[t] = (c + 3) & ~3;
    __syncthreads();
    for (int off = 128; off > 0; off >>= 1) {
        if (t < off) red[t] += red[t + off];
        __syncthreads();
    }
    if (t == 0) partTot[p] = red[0];
}

// ---- per-partition scatter (partition-base scan folded in) ----
__global__ void binB_scatter_kernel(const unsigned int* __restrict__ packed,
                                    const int* __restrict__ offs, const int* __restrict__ deg,
                                    const int* __restrict__ partTot, int* __restrict__ row_ptr,
                                    unsigned short* __restrict__ src_idx, int nChunks,
                                    int nPart, int N) {
    __shared__ int ps[256];
    __shared__ int pref[256];
    __shared__ int cur[256];
    int t = threadIdx.x;
    int p = blockIdx.x;
    ps[t] = (t < nPart) ? partTot[t] : 0;
    __syncthreads();
    for (int off = 1; off < 256; off <<= 1) {
        int u = (t >= off) ? ps[t - off] : 0;
        __syncthreads();
        ps[t] += u;
        __syncthreads();
    }
    int partBase = (p > 0) ? ps[p - 1] : 0;
    int node = p * 256 + t;
    int d = (node < N) ? deg[node] : 0;
    int a = (d + 3) & ~3;
    pref[t] = a;
    __syncthreads();
    for (int off = 1; off < 256; off <<= 1) {
        int u = (t >= off) ? pref[t - off] : 0;
        __syncthreads();
        pref[t] += u;
        __syncthreads();
    }
    int rp = partBase + pref[t] - a;
    if (node < N) row_ptr[node] = rp;
    cur[t] = rp;
    __syncthreads();
    for (int c = t; c < nChunks; c += 256) {
        const int* oc = offs + c * 257;
        int o0 = oc[p], o1 = oc[p + 1];
        const unsigned int* pk = packed + (size_t)c * CHUNK;
        for (int i = o0; i < o1; ++i) {
            unsigned int pr = pk[i];
            int ln = (pr >> 16) & 255;
            int slot = atomicAdd(&cur[ln], 1);
            src_idx[slot] = (unsigned short)(pr & 0xffffu);
        }
    }
}

// Mean aggregation over fp16 rows. Two nodes per wave; each 32-lane half:
// 4 groups x 8 lanes, 4 predicated slots/group (ushort4 index load).
__global__ void agg_mean8_kernel(const _Float16* __restrict__ h, const int* __restrict__ row_ptr,
                                 const int* __restrict__ degp,
                                 const unsigned short* __restrict__ src_idx,
                                 _Float16* __restrict__ h_out, int N) {
    int wid = (blockIdx.x * blockDim.x + threadIdx.x) >> 6;
    int lane = threadIdx.x & 63;
    int node = wid * 2 + (lane >> 5);
    if (node >= N) return;
    int lane32 = lane & 31;
    int beg = row_ptr[node];
    int dgr = degp[node];
    int end = beg + dgr;
    int j = lane32 >> 3, f = lane32 & 7;
    const uint4* rowp = (const uint4*)h;
    float acc[8];
    #pragma unroll
    for (int q = 0; q < 8; ++q) acc[q] = 0.f;
    for (int base = beg + 4 * j; base < end; base += 16) {
        ushort4 i4 = *(const ushort4*)(src_idx + base);
        unsigned short ss[4] = {i4.x, i4.y, i4.z, i4.w};
        #pragma unroll
        for (int k = 0; k < 4; ++k) {
            int e = base + k;
            int s = ss[k];
            uint4 raw = rowp[(size_t)s * 8 + f];
            if (e >= end) { raw.x = 0u; raw.y = 0u; raw.z = 0u; raw.w = 0u; }
            half8 v = *(half8*)&raw;
            #pragma unroll
            for (int q = 0; q < 8; ++q) acc[q] += (float)v[q];
        }
    }
    #pragma unroll
    for (int q = 0; q < 8; ++q) {
        acc[q] += __shfl_down(acc[q], 16, 64);
        acc[q] += __shfl_down(acc[q], 8, 64);
    }
    if (lane32 < 8) {
        float inv = dgr > 0 ? 1.f / (float)dgr : 0.f;
        half8 o;
        #pragma unroll
        for (int q = 0; q < 8; ++q) o[q] = (_Float16)(acc[q] * inv);
        *((half8*)h_out + (size_t)node * 8 + lane32) = o;
    }
}

// Smoothing pass 3 + xs build + conv1 attention dots (NO GEMV here).
// xs = (x+h1+h2+h3)/4 written fp16; a1/a2 per-node dots.
__global__ void mean3_xs_kernel(const _Float16* __restrict__ h /*h2*/,
                                const _Float16* __restrict__ x16,
                                const _Float16* __restrict__ hA /*h1*/,
                                const int* __restrict__ row_ptr, const int* __restrict__ degp,
                                const unsigned short* __restrict__ src_idx,
                                const float* __restrict__ W_att1,
                                _Float16* __restrict__ xs16, float* __restrict__ a1,
                                float* __restrict__ a2, int N) {
    int wid = (blockIdx.x * blockDim.x + threadIdx.x) >> 6;
    int lane = threadIdx.x & 63;
    int node = wid * 2 + (lane >> 5);
    if (node >= N) return;
    int lane32 = lane & 31;
    int beg = row_ptr[node];
    int dgr = degp[node];
    int end = beg + dgr;
    int j = lane32 >> 3, f = lane32 & 7;
    const uint4* rowp = (const uint4*)h;
    float acc[8];
    #pragma unroll
    for (int q = 0; q < 8; ++q) acc[q] = 0.f;
    for (int base = beg + 4 * j; base < end; base += 16) {
        ushort4 i4 = *(const ushort4*)(src_idx + base);
        unsigned short ss[4] = {i4.x, i4.y, i4.z, i4.w};
        #pragma unroll
        for (int k = 0; k < 4; ++k) {
            int e = base + k;
            int s = ss[k];
            uint4 raw = rowp[(size_t)s * 8 + f];
            if (e >= end) { raw.x = 0u; raw.y = 0u; raw.z = 0u; raw.w = 0u; }
            half8 v = *(half8*)&raw;
            #pragma unroll
            for (int q = 0; q < 8; ++q) acc[q] += (float)v[q];
        }
    }
    #pragma unroll
    for (int q = 0; q < 8; ++q) {
        acc[q] += __shfl_down(acc[q], 16, 64);
        acc[q] += __shfl_down(acc[q], 8, 64);
    }
    float p1 = 0.f, p2 = 0.f;
    if (lane32 < 8) {
        float inv = dgr > 0 ? 1.f / (float)dgr : 0.f;
        half8 xv = *((const half8*)x16 + (size_t)node * 8 + f);
        half8 h1v = *((const half8*)hA + (size_t)node * 8 + f);
        half8 h2v = *((const half8*)h + (size_t)node * 8 + f);
        half8 o;
        #pragma unroll
        for (int q = 0; q < 8; ++q) {
            float xsv = ((float)xv[q] + (float)h1v[q] + (float)h2v[q] + acc[q] * inv) * 0.25f;
            o[q] = (_Float16)xsv;
            p1 += xsv * W_att1[f * 8 + q];
            p2 += xsv * W_att1[64 + f * 8 + q];
        }
        *((half8*)xs16 + (size_t)node * 8 + f) = o;
    }
    p1 += __shfl_down(p1, 4, 64); p2 += __shfl_down(p2, 4, 64);
    p1 += __shfl_down(p1, 2, 64); p2 += __shfl_down(p2, 2, 64);
    p1 += __shfl_down(p1, 1, 64); p2 += __shfl_down(p2, 1, 64);
    if (lane32 == 0) { a1[node] = p1; a2[node] = p2; }
}

// z1 = xs @ W_lin1 (64x64): one node per wave, shfl-broadcast GEMV, no LDS.
__global__ void xform1z_kernel(const _Float16* __restrict__ xs16,
                               const float* __restrict__ W_lin1,
                               _Float16* __restrict__ z1, int N) {
    int n = (blockIdx.x * blockDim.x + threadIdx.x) >> 6;
    int lane = threadIdx.x & 63;
    if (n >= N) return;
    float xv = (float)xs16[(size_t)n * 64 + lane];
    float acc = 0.f;
    #pragma unroll
    for (int k = 0; k < 64; ++k) {
        float xk = __shfl(xv, k, 64);
        acc += xk * W_lin1[k * 64 + lane];
    }
    z1[(size_t)n * 64 + lane] = (_Float16)acc;
}

// Conv1 aggregation: gather z1 with leaky scores, relu -> h1 (fp16).
__global__ void agg_conv64_kernel(const _Float16* __restrict__ z, const float* __restrict__ a1v,
                                  const float* __restrict__ a2v, const float* __restrict__ b_att,
                                  const int* __restrict__ row_ptr, const int* __restrict__ degp,
                                  const unsigned short* __restrict__ src_idx,
                                  _Float16* __restrict__ h1out, int N) {
    int wid = (blockIdx.x * blockDim.x + threadIdx.x) >> 6;
    int lane = threadIdx.x & 63;
    int node = wid * 2 + (lane >> 5);
    if (node >= N) return;
    int lane32 = lane & 31;
    float ad = a2v[node] + b_att[0];
    int beg = row_ptr[node];
    int end = beg + degp[node];
    int j = lane32 >> 3, f = lane32 & 7;
    const uint4* rowp = (const uint4*)z;
    float acc[8];
    #pragma unroll
    for (int q = 0; q < 8; ++q) acc[q] = 0.f;
    for (int base = beg + 4 * j; base < end; base += 16) {
        ushort4 i4 = *(const ushort4*)(src_idx + base);
        unsigned short ss[4] = {i4.x, i4.y, i4.z, i4.w};
        #pragma unroll
        for (int k = 0; k < 4; ++k) {
            int e = base + k;
            int s = ss[k];
            float sc = a1v[s] + ad;
            sc = sc > 0.f ? sc : 0.01f * sc;
            uint4 raw = rowp[(size_t)s * 8 + f];
            if (e >= end) { raw.x = 0u; raw.y = 0u; raw.z = 0u; raw.w = 0u; }
            half8 v = *(half8*)&raw;
            #pragma unroll
            for (int q = 0; q < 8; ++q) acc[q] += sc * (float)v[q];
        }
    }
    #pragma unroll
    for (int q = 0; q < 8; ++q) {
        acc[q] += __shfl_down(acc[q], 16, 64);
        acc[q] += __shfl_down(acc[q], 8, 64);
    }
    if (lane32 < 8) {
        half8 o;
        #pragma unroll
        for (int q = 0; q < 8; ++q) o[q] = (_Float16)fmaxf(acc[q], 0.f);
        *((half8*)h1out + (size_t)node * 8 + lane32) = o;
    }
}

// z2 = h1 @ W_lin2 (64x32) + conv2 attention dots. One node per wave.
__global__ void xform2z_kernel(const _Float16* __restrict__ h1,
                               const float* __restrict__ W_lin2,
                               const float* __restrict__ W_att2,
                               float* __restrict__ z2, float* __restrict__ a1o,
                               float* __restrict__ a2o, int N) {
    int n = (blockIdx.x * blockDim.x + threadIdx.x) >> 6;
    int lane = threadIdx.x & 63;
    if (n >= N) return;
    float hv = (float)h1[(size_t)n * 64 + lane];
    float p1 = hv * W_att2[lane];
    float p2 = hv * W_att2[64 + lane];
    for (int off = 32; off > 0; off >>= 1) {
        p1 += __shfl_down(p1, off, 64);
        p2 += __shfl_down(p2, off, 64);
    }
    if (lane == 0) { a1o[n] = p1; a2o[n] = p2; }
    float acc = 0.f;
    int lane32 = lane & 31;
    #pragma unroll
    for (int k = 0; k < 64; ++k) {
        float hk = __shfl(hv, k, 64);
        if (lane < 32) acc += hk * W_lin2[k * 32 + lane32];
    }
    if (lane < 32) z2[(size_t)n * 32 + lane32] = acc;
}

// Conv2 aggregation: fp32 z2 rows (128B = 8 lanes x float4), two nodes/wave.
__global__ void agg_conv32_kernel(const float* __restrict__ z, const float* __restrict__ a1v,
                                  const float* __restrict__ a2v, const float* __restrict__ b_att,
                                  const int* __restrict__ row_ptr, const int* __restrict__ degp,
                                  const unsigned short* __restrict__ src_idx,
                                  float* __restrict__ outp, int N) {
    int wid = (blockIdx.x * blockDim.x + threadIdx.x) >> 6;
    int lane = threadIdx.x & 63;
    int node = wid * 2 + (lane >> 5);
    if (node >= N) return;
    int lane32 = lane & 31;
    float ad = a2v[node] + b_att[0];
    int beg = row_ptr[node];
    int end = beg + degp[node];
    int j = lane32 >> 3, f = lane32 & 7;
    const float4* rowp = (const float4*)z;
    float ax = 0.f, ay = 0.f, az = 0.f, aw = 0.f;
    for (int base = beg + 4 * j; base < end; base += 16) {
        ushort4 i4 = *(const ushort4*)(src_idx + base);
        unsigned short ss[4] = {i4.x, i4.y, i4.z, i4.w};
        #pragma unroll
        for (int k = 0; k < 4; ++k) {
            int e = base + k;
            int s = ss[k];
            float sc = a1v[s] + ad;
            sc = sc > 0.f ? sc : 0.01f * sc;
            if (e >= end) sc = 0.f;
            float4 v = rowp[(size_t)s * 8 + f];
            ax += sc * v.x; ay += sc * v.y; az += sc * v.z; aw += sc * v.w;
        }
    }
    ax += __shfl_down(ax, 16, 64); ay += __shfl_down(ay, 16, 64);
    az += __shfl_down(az, 16, 64); aw += __shfl_down(aw, 16, 64);
    ax += __shfl_down(ax, 8, 64);  ay += __shfl_down(ay, 8, 64);
    az += __shfl_down(az, 8, 64);  aw += __shfl_down(aw, 8, 64);
    if (lane32 < 8) {
        float4 o; o.x = ax; o.y = ay; o.z = az; o.w = aw;
        *((float4*)(outp + (size_t)node * 32) + lane32) = o;
    }
}

extern "C" void kernel_launch(void* const* d_in, const int* in_sizes, int n_in,
                              void* d_out, int out_size, void* d_ws, size_t ws_size,
                              hipStream_t stream) {
    const float* x      = (const float*)d_in[0];
    const int*   ei     = (const int*)d_in[1];
    const float* W_att1 = (const float*)d_in[2];
    const float* b_att1 = (const float*)d_in[3];
    const float* W_lin1 = (const float*)d_in[4];
    const float* W_att2 = (const float*)d_in[5];
    const float* b_att2 = (const float*)d_in[6];
    const float* W_lin2 = (const float*)d_in[7];
    float* out = (float*)d_out;

    int N = in_sizes[0] / 64;   // 50000 (< 65536, required for u16 indices)
    int E = in_sizes[1] / 2;
    const int* src = ei;
    const int* dst = ei + E;
    int nChunks = (E + CHUNK - 1) / CHUNK;   // 391
    int nPart   = (N + 255) >> 8;            // 196 (must be <= 256)

    char* ws = (char*)d_ws;
    size_t off = 0;
    auto alloc = [&](size_t bytes) -> void* {
        void* p = ws + off;
        off += (bytes + 255) & ~(size_t)255;
        return p;
    };
    int*            deg     = (int*)alloc((size_t)N * 4);
    int*            row_ptr = (int*)alloc((size_t)N * 4);
    unsigned short* src_idx = (unsigned short*)alloc(((size_t)E + 4 * N) * 2);
    unsigned int*   packed  = (unsigned int*)alloc((size_t)nChunks * CHUNK * 4);
    int*            offs    = (int*)alloc((size_t)nChunks * 257 * 4);
    int*            partTot = (int*)alloc((size_t)256 * 4);
    _Float16* x16 = (_Float16*)alloc((size_t)N * 64 * 2);
    _Float16* hA  = (_Float16*)alloc((size_t)N * 64 * 2);
    _Float16* hB  = (_Float16*)alloc((size_t)N * 64 * 2);
    _Float16* xs16 = (_Float16*)alloc((size_t)N * 64 * 2);
    _Float16* z1  = (_Float16*)alloc((size_t)N * 64 * 2);
    _Float16* h1f = (_Float16*)alloc((size_t)N * 64 * 2);
    float* z2  = (float*)alloc((size_t)N * 32 * 4);
    float* a1  = (float*)alloc((size_t)N * 4);
    float* a2  = (float*)alloc((size_t)N * 4);
    float* a1b = (float*)alloc((size_t)N * 4);
    float* a2b = (float*)alloc((size_t)N * 4);

    const int tb = 256;
    int total8 = N * 8;

    binA_kernel<<<nChunks, 256, 0, stream>>>(src, dst, packed, offs, x, x16, total8, E);
    binB_count_kernel<<<nPart, 256, 0, stream>>>(packed, offs, deg, partTot, nChunks, N);
    binB_scatter_kernel<<<nPart, 256, 0, stream>>>(packed, offs, deg, partTot, row_ptr,
                                                   src_idx, nChunks, nPart, N);

    int gBlocks = (N + 7) / 8;   // two nodes per wave, 4 waves/block
    int xBlocks = (N + 3) / 4;   // one node per wave
    agg_mean8_kernel<<<gBlocks, tb, 0, stream>>>(x16, row_ptr, deg, src_idx, hA, N);
    agg_mean8_kernel<<<gBlocks, tb, 0, stream>>>(hA,  row_ptr, deg, src_idx, hB, N);
    mean3_xs_kernel<<<gBlocks, tb, 0, stream>>>(hB, x16, hA, row_ptr, deg, src_idx,
                                                W_att1, xs16, a1, a2, N);
    xform1z_kernel<<<xBlocks, tb, 0, stream>>>(xs16, W_lin1, z1, N);
    agg_conv64_kernel<<<gBlocks, tb, 0, stream>>>(z1, a1, a2, b_att1, row_ptr, deg, src_idx,
                                                  h1f, N);
    xform2z_kernel<<<xBlocks, tb, 0, stream>>>(h1f, W_lin2, W_att2, z2, a1b, a2b, N);
    agg_conv32_kernel<<<gBlocks, tb, 0, stream>>>(z2, a1b, a2b, b_att2, row_ptr, deg, src_idx,
                                                  out, N);
}

// Round 13
// 252.519 us; speedup vs baseline: 1.1641x; 1.1641x over previous
//
#include <hip/hip_runtime.h>

// DeformableGCN: 3x mean-smoothing + 2x attention-weighted GCN conv.
// R7-R10: branchless half8 gathers, two nodes/wave, partition-parallel
// LDS bin-sort CSR, ushort4 index loads.
// R12: slim gathers (xs build + attention dots only) + separate GEMV kernels.
// R12 FAILURE: shfl-broadcast GEMV at VGPR=8 = serialized bpermute chain,
// 72us each. R13: transforms use the R10-proven LDS-row structure (stage row
// in LDS once, per-k same-address broadcast reads pipeline; W from L1).

typedef __attribute__((ext_vector_type(8))) _Float16 half8;

#define CHUNK 2048

// ---- pass A: bin edges into partition-sorted chunks + x->fp16 convert ----
__global__ void binA_kernel(const int* __restrict__ src, const int* __restrict__ dst,
                            unsigned int* __restrict__ packed, int* __restrict__ offs,
                            const float* __restrict__ x, _Float16* __restrict__ x16,
                            int total8, int E) {
    __shared__ int cnt[256];
    __shared__ int pref[256];
    __shared__ int cur[256];
    __shared__ unsigned int stage[CHUNK];
    int t = threadIdx.x;
    int base = blockIdx.x * CHUNK;
    int len = E - base; if (len > CHUNK) len = CHUNK;
    cnt[t] = 0;
    __syncthreads();
    for (int i = t; i < len; i += 256) atomicAdd(&cnt[dst[base + i] >> 8], 1);
    __syncthreads();
    int v = cnt[t];
    pref[t] = v;
    __syncthreads();
    for (int off = 1; off < 256; off <<= 1) {
        int u = (t >= off) ? pref[t - off] : 0;
        __syncthreads();
        pref[t] += u;
        __syncthreads();
    }
    int excl = pref[t] - v;
    cur[t] = excl;
    offs[blockIdx.x * 257 + t] = excl;
    if (t == 255) offs[blockIdx.x * 257 + 256] = pref[255];
    __syncthreads();
    for (int i = t; i < len; i += 256) {
        int s = src[base + i], d = dst[base + i];
        int pos = atomicAdd(&cur[d >> 8], 1);
        stage[pos] = (unsigned int)s | ((unsigned int)d << 16);
    }
    __syncthreads();
    for (int i = t; i < len; i += 256) packed[base + i] = stage[i];
    for (int i = blockIdx.x * 256 + t; i < total8; i += gridDim.x * 256) {
        float4 v0 = ((const float4*)x)[2 * i];
        float4 v1 = ((const float4*)x)[2 * i + 1];
        half8 o;
        o[0] = (_Float16)v0.x; o[1] = (_Float16)v0.y; o[2] = (_Float16)v0.z; o[3] = (_Float16)v0.w;
        o[4] = (_Float16)v1.x; o[5] = (_Float16)v1.y; o[6] = (_Float16)v1.z; o[7] = (_Float16)v1.w;
        ((half8*)x16)[i] = o;
    }
}

// ---- per-partition degree count: dense deg write + aligned total ----
__global__ void binB_count_kernel(const unsigned int* __restrict__ packed,
                                  const int* __restrict__ offs,
                                  int* __restrict__ deg, int* __restrict__ partTot,
                                  int nChunks, int N) {
    __shared__ int cnt[256];
    __shared__ int red[256];
    int t = threadIdx.x;
    int p = blockIdx.x;
    cnt[t] = 0;
    __syncthreads();
    for (int c = t; c < nChunks; c += 256) {
        const int* oc = offs + c * 257;
        int o0 = oc[p], o1 = oc[p + 1];
        const unsigned int* pk = packed + (size_t)c * CHUNK;
        for (int i = o0; i < o1; ++i) atomicAdd(&cnt[(pk[i] >> 16) & 255], 1);
    }
    __syncthreads();
    int node = p * 256 + t;
    int c = cnt[t];
    if (node < N) deg[node] = c;
    red[t] = (c + 3) & ~3;
    __syncthreads();
    for (int off = 128; off > 0; off >>= 1) {
        if (t < off) red[t] += red[t + off];
        __syncthreads();
    }
    if (t == 0) partTot[p] = red[0];
}

// ---- per-partition scatter (partition-base scan folded in) ----
__global__ void binB_scatter_kernel(const unsigned int* __restrict__ packed,
                                    const int* __restrict__ offs, const int* __restrict__ deg,
                                    const int* __restrict__ partTot, int* __restrict__ row_ptr,
                                    unsigned short* __restrict__ src_idx, int nChunks,
                                    int nPart, int N) {
    __shared__ int ps[256];
    __shared__ int pref[256];
    __shared__ int cur[256];
    int t = threadIdx.x;
    int p = blockIdx.x;
    ps[t] = (t < nPart) ? partTot[t] : 0;
    __syncthreads();
    for (int off = 1; off < 256; off <<= 1) {
        int u = (t >= off) ? ps[t - off] : 0;
        __syncthreads();
        ps[t] += u;
        __syncthreads();
    }
    int partBase = (p > 0) ? ps[p - 1] : 0;
    int node = p * 256 + t;
    int d = (node < N) ? deg[node] : 0;
    int a = (d + 3) & ~3;
    pref[t] = a;
    __syncthreads();
    for (int off = 1; off < 256; off <<= 1) {
        int u = (t >= off) ? pref[t - off] : 0;
        __syncthreads();
        pref[t] += u;
        __syncthreads();
    }
    int rp = partBase + pref[t] - a;
    if (node < N) row_ptr[node] = rp;
    cur[t] = rp;
    __syncthreads();
    for (int c = t; c < nChunks; c += 256) {
        const int* oc = offs + c * 257;
        int o0 = oc[p], o1 = oc[p + 1];
        const unsigned int* pk = packed + (size_t)c * CHUNK;
        for (int i = o0; i < o1; ++i) {
            unsigned int pr = pk[i];
            int ln = (pr >> 16) & 255;
            int slot = atomicAdd(&cur[ln], 1);
            src_idx[slot] = (unsigned short)(pr & 0xffffu);
        }
    }
}

// Mean aggregation over fp16 rows. Two nodes per wave; each 32-lane half:
// 4 groups x 8 lanes, 4 predicated slots/group (ushort4 index load).
__global__ void agg_mean8_kernel(const _Float16* __restrict__ h, const int* __restrict__ row_ptr,
                                 const int* __restrict__ degp,
                                 const unsigned short* __restrict__ src_idx,
                                 _Float16* __restrict__ h_out, int N) {
    int wid = (blockIdx.x * blockDim.x + threadIdx.x) >> 6;
    int lane = threadIdx.x & 63;
    int node = wid * 2 + (lane >> 5);
    if (node >= N) return;
    int lane32 = lane & 31;
    int beg = row_ptr[node];
    int dgr = degp[node];
    int end = beg + dgr;
    int j = lane32 >> 3, f = lane32 & 7;
    const uint4* rowp = (const uint4*)h;
    float acc[8];
    #pragma unroll
    for (int q = 0; q < 8; ++q) acc[q] = 0.f;
    for (int base = beg + 4 * j; base < end; base += 16) {
        ushort4 i4 = *(const ushort4*)(src_idx + base);
        unsigned short ss[4] = {i4.x, i4.y, i4.z, i4.w};
        #pragma unroll
        for (int k = 0; k < 4; ++k) {
            int e = base + k;
            int s = ss[k];
            uint4 raw = rowp[(size_t)s * 8 + f];
            if (e >= end) { raw.x = 0u; raw.y = 0u; raw.z = 0u; raw.w = 0u; }
            half8 v = *(half8*)&raw;
            #pragma unroll
            for (int q = 0; q < 8; ++q) acc[q] += (float)v[q];
        }
    }
    #pragma unroll
    for (int q = 0; q < 8; ++q) {
        acc[q] += __shfl_down(acc[q], 16, 64);
        acc[q] += __shfl_down(acc[q], 8, 64);
    }
    if (lane32 < 8) {
        float inv = dgr > 0 ? 1.f / (float)dgr : 0.f;
        half8 o;
        #pragma unroll
        for (int q = 0; q < 8; ++q) o[q] = (_Float16)(acc[q] * inv);
        *((half8*)h_out + (size_t)node * 8 + lane32) = o;
    }
}

// Smoothing pass 3 + xs build + conv1 attention dots (no GEMV).
__global__ void mean3_xs_kernel(const _Float16* __restrict__ h /*h2*/,
                                const _Float16* __restrict__ x16,
                                const _Float16* __restrict__ hA /*h1*/,
                                const int* __restrict__ row_ptr, const int* __restrict__ degp,
                                const unsigned short* __restrict__ src_idx,
                                const float* __restrict__ W_att1,
                                _Float16* __restrict__ xs16, float* __restrict__ a1,
                                float* __restrict__ a2, int N) {
    int wid = (blockIdx.x * blockDim.x + threadIdx.x) >> 6;
    int lane = threadIdx.x & 63;
    int node = wid * 2 + (lane >> 5);
    if (node >= N) return;
    int lane32 = lane & 31;
    int beg = row_ptr[node];
    int dgr = degp[node];
    int end = beg + dgr;
    int j = lane32 >> 3, f = lane32 & 7;
    const uint4* rowp = (const uint4*)h;
    float acc[8];
    #pragma unroll
    for (int q = 0; q < 8; ++q) acc[q] = 0.f;
    for (int base = beg + 4 * j; base < end; base += 16) {
        ushort4 i4 = *(const ushort4*)(src_idx + base);
        unsigned short ss[4] = {i4.x, i4.y, i4.z, i4.w};
        #pragma unroll
        for (int k = 0; k < 4; ++k) {
            int e = base + k;
            int s = ss[k];
            uint4 raw = rowp[(size_t)s * 8 + f];
            if (e >= end) { raw.x = 0u; raw.y = 0u; raw.z = 0u; raw.w = 0u; }
            half8 v = *(half8*)&raw;
            #pragma unroll
            for (int q = 0; q < 8; ++q) acc[q] += (float)v[q];
        }
    }
    #pragma unroll
    for (int q = 0; q < 8; ++q) {
        acc[q] += __shfl_down(acc[q], 16, 64);
        acc[q] += __shfl_down(acc[q], 8, 64);
    }
    float p1 = 0.f, p2 = 0.f;
    if (lane32 < 8) {
        float inv = dgr > 0 ? 1.f / (float)dgr : 0.f;
        half8 xv = *((const half8*)x16 + (size_t)node * 8 + f);
        half8 h1v = *((const half8*)hA + (size_t)node * 8 + f);
        half8 h2v = *((const half8*)h + (size_t)node * 8 + f);
        half8 o;
        #pragma unroll
        for (int q = 0; q < 8; ++q) {
            float xsv = ((float)xv[q] + (float)h1v[q] + (float)h2v[q] + acc[q] * inv) * 0.25f;
            o[q] = (_Float16)xsv;
            p1 += xsv * W_att1[f * 8 + q];
            p2 += xsv * W_att1[64 + f * 8 + q];
        }
        *((half8*)xs16 + (size_t)node * 8 + f) = o;
    }
    p1 += __shfl_down(p1, 4, 64); p2 += __shfl_down(p2, 4, 64);
    p1 += __shfl_down(p1, 2, 64); p2 += __shfl_down(p2, 2, 64);
    p1 += __shfl_down(p1, 1, 64); p2 += __shfl_down(p2, 1, 64);
    if (lane32 == 0) { a1[node] = p1; a2[node] = p2; }
}

// z1 = xs @ W_lin1 (64x64): LDS-row staging (R10-proven structure).
__global__ void xform1L_kernel(const _Float16* __restrict__ xs16,
                               const float* __restrict__ W_lin1,
                               _Float16* __restrict__ z1, int N) {
    __shared__ float row[4][64];
    int wib = threadIdx.x >> 6;
    int lane = threadIdx.x & 63;
    int n = blockIdx.x * 4 + wib;
    int nc = n < N ? n : N - 1;
    row[wib][lane] = (float)xs16[(size_t)nc * 64 + lane];
    __syncthreads();
    float acc = 0.f;
    #pragma unroll
    for (int k = 0; k < 64; ++k) acc += row[wib][k] * W_lin1[k * 64 + lane];
    if (n < N) z1[(size_t)n * 64 + lane] = (_Float16)acc;
}

// Conv1 aggregation: gather z1 with leaky scores, relu -> h1 (fp16).
__global__ void agg_conv64_kernel(const _Float16* __restrict__ z, const float* __restrict__ a1v,
                                  const float* __restrict__ a2v, const float* __restrict__ b_att,
                                  const int* __restrict__ row_ptr, const int* __restrict__ degp,
                                  const unsigned short* __restrict__ src_idx,
                                  _Float16* __restrict__ h1out, int N) {
    int wid = (blockIdx.x * blockDim.x + threadIdx.x) >> 6;
    int lane = threadIdx.x & 63;
    int node = wid * 2 + (lane >> 5);
    if (node >= N) return;
    int lane32 = lane & 31;
    float ad = a2v[node] + b_att[0];
    int beg = row_ptr[node];
    int end = beg + degp[node];
    int j = lane32 >> 3, f = lane32 & 7;
    const uint4* rowp = (const uint4*)z;
    float acc[8];
    #pragma unroll
    for (int q = 0; q < 8; ++q) acc[q] = 0.f;
    for (int base = beg + 4 * j; base < end; base += 16) {
        ushort4 i4 = *(const ushort4*)(src_idx + base);
        unsigned short ss[4] = {i4.x, i4.y, i4.z, i4.w};
        #pragma unroll
        for (int k = 0; k < 4; ++k) {
            int e = base + k;
            int s = ss[k];
            float sc = a1v[s] + ad;
            sc = sc > 0.f ? sc : 0.01f * sc;
            uint4 raw = rowp[(size_t)s * 8 + f];
            if (e >= end) { raw.x = 0u; raw.y = 0u; raw.z = 0u; raw.w = 0u; }
            half8 v = *(half8*)&raw;
            #pragma unroll
            for (int q = 0; q < 8; ++q) acc[q] += sc * (float)v[q];
        }
    }
    #pragma unroll
    for (int q = 0; q < 8; ++q) {
        acc[q] += __shfl_down(acc[q], 16, 64);
        acc[q] += __shfl_down(acc[q], 8, 64);
    }
    if (lane32 < 8) {
        half8 o;
        #pragma unroll
        for (int q = 0; q < 8; ++q) o[q] = (_Float16)fmaxf(acc[q], 0.f);
        *((half8*)h1out + (size_t)node * 8 + lane32) = o;
    }
}

// z2 = h1 @ W_lin2 (64x32) + conv2 attention dots: LDS-row staging.
__global__ void xform2L_kernel(const _Float16* __restrict__ h1,
                               const float* __restrict__ W_lin2,
                               const float* __restrict__ W_att2,
                               float* __restrict__ z2, float* __restrict__ a1o,
                               float* __restrict__ a2o, int N) {
    __shared__ float row[4][64];
    int wib = threadIdx.x >> 6;
    int lane = threadIdx.x & 63;
    int n = blockIdx.x * 4 + wib;
    int nc = n < N ? n : N - 1;
    float hv = (float)h1[(size_t)nc * 64 + lane];
    row[wib][lane] = hv;
    __syncthreads();
    float p1 = hv * W_att2[lane];
    float p2 = hv * W_att2[64 + lane];
    for (int off = 32; off > 0; off >>= 1) {
        p1 += __shfl_down(p1, off, 64);
        p2 += __shfl_down(p2, off, 64);
    }
    float acc = 0.f;
    if (lane < 32) {
        #pragma unroll
        for (int k = 0; k < 64; ++k) acc += row[wib][k] * W_lin2[k * 32 + lane];
    }
    if (n < N) {
        if (lane < 32) z2[(size_t)n * 32 + lane] = acc;
        if (lane == 0) { a1o[n] = p1; a2o[n] = p2; }
    }
}

// Conv2 aggregation: fp32 z2 rows (128B = 8 lanes x float4), two nodes/wave.
__global__ void agg_conv32_kernel(const float* __restrict__ z, const float* __restrict__ a1v,
                                  const float* __restrict__ a2v, const float* __restrict__ b_att,
                                  const int* __restrict__ row_ptr, const int* __restrict__ degp,
                                  const unsigned short* __restrict__ src_idx,
                                  float* __restrict__ outp, int N) {
    int wid = (blockIdx.x * blockDim.x + threadIdx.x) >> 6;
    int lane = threadIdx.x & 63;
    int node = wid * 2 + (lane >> 5);
    if (node >= N) return;
    int lane32 = lane & 31;
    float ad = a2v[node] + b_att[0];
    int beg = row_ptr[node];
    int end = beg + degp[node];
    int j = lane32 >> 3, f = lane32 & 7;
    const float4* rowp = (const float4*)z;
    float ax = 0.f, ay = 0.f, az = 0.f, aw = 0.f;
    for (int base = beg + 4 * j; base < end; base += 16) {
        ushort4 i4 = *(const ushort4*)(src_idx + base);
        unsigned short ss[4] = {i4.x, i4.y, i4.z, i4.w};
        #pragma unroll
        for (int k = 0; k < 4; ++k) {
            int e = base + k;
            int s = ss[k];
            float sc = a1v[s] + ad;
            sc = sc > 0.f ? sc : 0.01f * sc;
            if (e >= end) sc = 0.f;
            float4 v = rowp[(size_t)s * 8 + f];
            ax += sc * v.x; ay += sc * v.y; az += sc * v.z; aw += sc * v.w;
        }
    }
    ax += __shfl_down(ax, 16, 64); ay += __shfl_down(ay, 16, 64);
    az += __shfl_down(az, 16, 64); aw += __shfl_down(aw, 16, 64);
    ax += __shfl_down(ax, 8, 64);  ay += __shfl_down(ay, 8, 64);
    az += __shfl_down(az, 8, 64);  aw += __shfl_down(aw, 8, 64);
    if (lane32 < 8) {
        float4 o; o.x = ax; o.y = ay; o.z = az; o.w = aw;
        *((float4*)(outp + (size_t)node * 32) + lane32) = o;
    }
}

extern "C" void kernel_launch(void* const* d_in, const int* in_sizes, int n_in,
                              void* d_out, int out_size, void* d_ws, size_t ws_size,
                              hipStream_t stream) {
    const float* x      = (const float*)d_in[0];
    const int*   ei     = (const int*)d_in[1];
    const float* W_att1 = (const float*)d_in[2];
    const float* b_att1 = (const float*)d_in[3];
    const float* W_lin1 = (const float*)d_in[4];
    const float* W_att2 = (const float*)d_in[5];
    const float* b_att2 = (const float*)d_in[6];
    const float* W_lin2 = (const float*)d_in[7];
    float* out = (float*)d_out;

    int N = in_sizes[0] / 64;   // 50000 (< 65536, required for u16 indices)
    int E = in_sizes[1] / 2;
    const int* src = ei;
    const int* dst = ei + E;
    int nChunks = (E + CHUNK - 1) / CHUNK;   // 391
    int nPart   = (N + 255) >> 8;            // 196 (must be <= 256)

    char* ws = (char*)d_ws;
    size_t off = 0;
    auto alloc = [&](size_t bytes) -> void* {
        void* p = ws + off;
        off += (bytes + 255) & ~(size_t)255;
        return p;
    };
    int*            deg     = (int*)alloc((size_t)N * 4);
    int*            row_ptr = (int*)alloc((size_t)N * 4);
    unsigned short* src_idx = (unsigned short*)alloc(((size_t)E + 4 * N) * 2);
    unsigned int*   packed  = (unsigned int*)alloc((size_t)nChunks * CHUNK * 4);
    int*            offs    = (int*)alloc((size_t)nChunks * 257 * 4);
    int*            partTot = (int*)alloc((size_t)256 * 4);
    _Float16* x16 = (_Float16*)alloc((size_t)N * 64 * 2);
    _Float16* hA  = (_Float16*)alloc((size_t)N * 64 * 2);
    _Float16* hB  = (_Float16*)alloc((size_t)N * 64 * 2);
    _Float16* xs16 = (_Float16*)alloc((size_t)N * 64 * 2);
    _Float16* z1  = (_Float16*)alloc((size_t)N * 64 * 2);
    _Float16* h1f = (_Float16*)alloc((size_t)N * 64 * 2);
    float* z2  = (float*)alloc((size_t)N * 32 * 4);
    float* a1  = (float*)alloc((size_t)N * 4);
    float* a2  = (float*)alloc((size_t)N * 4);
    float* a1b = (float*)alloc((size_t)N * 4);
    float* a2b = (float*)alloc((size_t)N * 4);

    const int tb = 256;
    int total8 = N * 8;

    binA_kernel<<<nChunks, 256, 0, stream>>>(src, dst, packed, offs, x, x16, total8, E);
    binB_count_kernel<<<nPart, 256, 0, stream>>>(packed, offs, deg, partTot, nChunks, N);
    binB_scatter_kernel<<<nPart, 256, 0, stream>>>(packed, offs, deg, partTot, row_ptr,
                                                   src_idx, nChunks, nPart, N);

    int gBlocks = (N + 7) / 8;   // two nodes per wave, 4 waves/block
    int xBlocks = (N + 3) / 4;   // one node per wave
    agg_mean8_kernel<<<gBlocks, tb, 0, stream>>>(x16, row_ptr, deg, src_idx, hA, N);
    agg_mean8_kernel<<<gBlocks, tb, 0, stream>>>(hA,  row_ptr, deg, src_idx, hB, N);
    mean3_xs_kernel<<<gBlocks, tb, 0, stream>>>(hB, x16, hA, row_ptr, deg, src_idx,
                                                W_att1, xs16, a1, a2, N);
    xform1L_kernel<<<xBlocks, tb, 0, stream>>>(xs16, W_lin1, z1, N);
    agg_conv64_kernel<<<gBlocks, tb, 0, stream>>>(z1, a1, a2, b_att1, row_ptr, deg, src_idx,
                                                  h1f, N);
    xform2L_kernel<<<xBlocks, tb, 0, stream>>>(h1f, W_lin2, W_att2, z2, a1b, a2b, N);
    agg_conv32_kernel<<<gBlocks, tb, 0, stream>>>(z2, a1b, a2b, b_att2, row_ptr, deg, src_idx,
                                                  out, N);
}